// Round 7
// baseline (17.012 us; speedup 1.0000x reference)
//
#include <hip/hip_runtime.h>

// GCNCountry: out = ((leaky(leaky(adj@(x@Wgc)+bgc) @ W1 + b1) * dropmask) @ W2 + b2)[0]
// -> depends ONLY on row 0 of every intermediate. Vector chain:
//    v  = adj[0,:] @ x            (16 MB x-read, K1, 256 blocks -> 32 partials)
//    h0 = v @ Wgc; h1 = leaky(h0+bgc) @ W1; out = dropout(leaky(h1+b1)).W2+b2
//       -> K23 (32 blocks, one k-chunk of 32 each, NO redundancy):
//          preload Wgc/W1 slabs + finalize operands into REGISTERS while
//          phase A resolves; last-arriving block finalizes (t0-only fences).
//
// Cost model (R1-R6): in-graph node gap ~1us; kernel body ~1us+; fixed
// F+K1 ~ 11.5us; spin barrier ~10us (never); per-thread agent fences bad
// (R5); last-arrive with t0-only release/acquire ~free (R6, absmax 0).
// This round: cut K23's serialized latency exposures via issue-early/
// consume-late preloads (T14) and redundancy removal.

constexpr int N_FEAT  = 512;
constexpr int N_HID1  = 1024;
constexpr int N_HID2  = 512;
constexpr float SLOPE  = 0.01f;
constexpr float DROP_P = 0.3f;

constexpr int VP_N   = 32;      // v partials [32][512]
constexpr int VP_OFF = 0;
constexpr int H1_OFF = 16384;   // h1 partials [32][512]
constexpr int CNT_OFF = 32768;  // 1 int, zeroed by K1 each call
constexpr int NBLK2  = 32;      // K23 grid: 32 k-chunks of 32

__device__ __forceinline__ float leaky(float x) { return x >= 0.f ? x : SLOPE * x; }

// ---------------- K1: v_part[rb][c] = sum_{rows in chunk rb} adj0[row] * x[row][c] ----------------
// grid (8 col-stripes of 64, 32 row-chunks of 256), 256 thr; float4 fully-coalesced x reads.
__global__ __launch_bounds__(256) void k1_adjrow_x(const float* __restrict__ x,
                                                   const float* __restrict__ adj0,
                                                   float* __restrict__ vp,
                                                   int* __restrict__ cnt) {
    const int tid = threadIdx.x;
    if (blockIdx.x == 0 && blockIdx.y == 0 && tid == 0) cnt[0] = 0;  // visible at kernel boundary

    const int f4  = tid & 15;
    const int r   = tid >> 4;          // 0..15
    const int c0  = blockIdx.x * 64;   // col stripe
    const int rb  = blockIdx.y;        // row chunk
    const float4* x4 = reinterpret_cast<const float4*>(x);

    float4 acc = {0.f, 0.f, 0.f, 0.f};
    int row = rb * 256 + r;
    #pragma unroll
    for (int it = 0; it < 16; ++it, row += 16) {
        const float  a  = adj0[row];
        const float4 xv = x4[row * (N_FEAT / 4) + (c0 >> 2) + f4];
        acc.x = fmaf(a, xv.x, acc.x);
        acc.y = fmaf(a, xv.y, acc.y);
        acc.z = fmaf(a, xv.z, acc.z);
        acc.w = fmaf(a, xv.w, acc.w);
    }

    __shared__ float4 sm[256];
    sm[tid] = acc;
    __syncthreads();
    #pragma unroll
    for (int off = 128; off >= 16; off >>= 1) {
        if (tid < off) {
            float4 o = sm[tid + off];
            sm[tid].x += o.x; sm[tid].y += o.y; sm[tid].z += o.z; sm[tid].w += o.w;
        }
        __syncthreads();
    }
    if (tid < 16)
        reinterpret_cast<float4*>(vp + rb * N_FEAT + c0)[tid] = sm[tid];
}

// ---------------- K23: one k-chunk of 32 per block; preloads; last-arrive finalize ----------------
__global__ __launch_bounds__(256, 1) void k23_fused(const float* __restrict__ vp,
                                                    const float* __restrict__ Wgc,
                                                    const float* __restrict__ bgc,
                                                    const float* __restrict__ W1,
                                                    const float* __restrict__ b1,
                                                    const float* __restrict__ W2,
                                                    const float* __restrict__ b2,
                                                    const float* __restrict__ du0,
                                                    float* __restrict__ h1p,
                                                    int* __restrict__ cnt,
                                                    float* __restrict__ out) {
    const int t  = threadIdx.x;
    const int kc = blockIdx.x;          // 0..31
    const int k0 = kc * 32;             // h0-chunk [k0, k0+32)

    __shared__ float4 va[128];          // phase-A scratch
    __shared__ float4 vl4[128];         // full v (512 floats)
    __shared__ float  smb[32][33];      // phase-B m-group partials (padded)
    __shared__ float  hl[32];           // leaky(h0+bgc) chunk

    // ---- Phase A loads: issued FIRST (consumed first) ----
    const float4* vp4 = reinterpret_cast<const float4*>(vp);
    const int slot = t & 127;
    const int ph   = t >> 7;            // 0,1
    float4 a = {0.f, 0.f, 0.f, 0.f};
    #pragma unroll
    for (int p = 0; p < 16; ++p) {
        const float4 xv = vp4[(ph * 16 + p) * 128 + slot];
        a.x += xv.x; a.y += xv.y; a.z += xv.z; a.w += xv.w;
    }

    // ---- Preloads: issued while phase A is resolving, consumed in B/C/D ----
    // Wgc slab [512 m][32 k]: q = k-quad, mrow = m row group
    const float4* Wgc4 = reinterpret_cast<const float4*>(Wgc);
    const int q = t & 7, mrow = t >> 3;  // q: 0..7, mrow: 0..31
    float4 wreg[16];
    #pragma unroll
    for (int p = 0; p < 16; ++p)
        wreg[p] = Wgc4[(p * 32 + mrow) * (N_HID1 / 4) + (k0 >> 2) + q];

    // W1 slab [32 k][512 j]: thread owns j = 2t, 2t+1
    float2 w1reg[32];
    #pragma unroll
    for (int k = 0; k < 32; ++k)
        w1reg[k] = *reinterpret_cast<const float2*>(&W1[(k0 + k) * N_HID2 + 2 * t]);

    // finalize operands (read-only inputs: no acquire ordering needed)
    const float2 pb1 = *reinterpret_cast<const float2*>(&b1[2 * t]);
    const float2 pW2 = *reinterpret_cast<const float2*>(&W2[2 * t]);
    const float2 pdu = *reinterpret_cast<const float2*>(&du0[2 * t]);
    const float  pbgc = bgc[k0 + (t & 31)];
    const float  pb2  = b2[0];

    // ---- Phase A finish: reduce the two halves in LDS ----
    if (ph == 0) va[slot] = a;
    __syncthreads();
    if (ph == 1) {
        float4 o = va[slot];
        o.x += a.x; o.y += a.y; o.z += a.z; o.w += a.w;
        vl4[slot] = o;
    }
    __syncthreads();
    const float* vl = reinterpret_cast<const float*>(vl4);

    // ---- Phase B: h0[k0+q*4 .. +3] partial over m-groups, from registers ----
    {
        float4 acc = {0.f, 0.f, 0.f, 0.f};
        #pragma unroll
        for (int p = 0; p < 16; ++p) {
            const float vm = vl[p * 32 + mrow];
            acc.x = fmaf(vm, wreg[p].x, acc.x);
            acc.y = fmaf(vm, wreg[p].y, acc.y);
            acc.z = fmaf(vm, wreg[p].z, acc.z);
            acc.w = fmaf(vm, wreg[p].w, acc.w);
        }
        smb[mrow][q * 4 + 0] = acc.x;
        smb[mrow][q * 4 + 1] = acc.y;
        smb[mrow][q * 4 + 2] = acc.z;
        smb[mrow][q * 4 + 3] = acc.w;
        __syncthreads();
        if (t < 32) {
            float s = pbgc;
            #pragma unroll
            for (int r = 0; r < 32; ++r) s += smb[r][t];
            hl[t] = leaky(s);
        }
        __syncthreads();
    }

    // ---- Phase C: h1 partial row (512 j) from registers ----
    {
        float2 acc = {0.f, 0.f};
        #pragma unroll
        for (int k = 0; k < 32; ++k) {
            acc.x = fmaf(hl[k], w1reg[k].x, acc.x);
            acc.y = fmaf(hl[k], w1reg[k].y, acc.y);
        }
        *reinterpret_cast<float2*>(&h1p[kc * N_HID2 + 2 * t]) = acc;
    }

    // ---- last-arrive: t0-only release; only the 32nd block pays an acquire ----
    __shared__ int amLast;
    __syncthreads();   // drains this block's h1p stores (vmcnt(0) before s_barrier)
    if (t == 0) {
        int old = __hip_atomic_fetch_add(cnt, 1, __ATOMIC_RELEASE, __HIP_MEMORY_SCOPE_AGENT);
        amLast = (old == NBLK2 - 1);
    }
    __syncthreads();
    if (!amLast) return;
    if (t == 0)  // single acquire: make all blocks' h1p stores visible
        (void)__hip_atomic_load(cnt, __ATOMIC_ACQUIRE, __HIP_MEMORY_SCOPE_AGENT);
    __syncthreads();

    // ---- Phase D: reduce 32 h1 partials, bias+leaky+dropout, dot W2[:,0], +b2 ----
    {
        float s0 = pb1.x, s1 = pb1.y;
        #pragma unroll
        for (int p = 0; p < NBLK2; ++p) {
            const float2 hp = *reinterpret_cast<const float2*>(&h1p[p * N_HID2 + 2 * t]);
            s0 += hp.x; s1 += hp.y;
        }
        float ha = leaky(s0), hb = leaky(s1);
        ha = (pdu.x >= DROP_P) ? ha / (1.0f - DROP_P) : 0.f;
        hb = (pdu.y >= DROP_P) ? hb / (1.0f - DROP_P) : 0.f;
        float term = fmaf(ha, pW2.x, hb * pW2.y);

        #pragma unroll
        for (int off = 32; off; off >>= 1) term += __shfl_down(term, off, 64);
        __shared__ float red[4];
        if ((t & 63) == 0) red[t >> 6] = term;
        __syncthreads();
        if (t == 0)
            out[0] = red[0] + red[1] + red[2] + red[3] + pb2;
    }
}

extern "C" void kernel_launch(void* const* d_in, const int* in_sizes, int n_in,
                              void* d_out, int out_size, void* d_ws, size_t ws_size,
                              hipStream_t stream) {
    const float* x   = (const float*)d_in[0];
    const float* adj = (const float*)d_in[1];  // row 0 = first 8192 floats
    const float* Wgc = (const float*)d_in[2];
    const float* bgc = (const float*)d_in[3];
    const float* W1  = (const float*)d_in[4];
    const float* b1  = (const float*)d_in[5];
    const float* W2  = (const float*)d_in[6];
    const float* b2  = (const float*)d_in[7];
    const float* du  = (const float*)d_in[8];  // row 0 = first 512 floats
    float* out = (float*)d_out;
    float* ws  = (float*)d_ws;

    float* vp  = ws + VP_OFF;
    float* h1p = ws + H1_OFF;
    int*   cnt = (int*)(ws + CNT_OFF);

    k1_adjrow_x<<<dim3(8, 32), 256, 0, stream>>>(x, adj, vp, cnt);
    k23_fused  <<<dim3(NBLK2), 256, 0, stream>>>(vp, Wgc, bgc, W1, b1, W2, b2, du,
                                                 h1p, cnt, out);
}